// Round 2
// baseline (201325.610 us; speedup 1.0000x reference)
//
#include <hip/hip_runtime.h>
#include <cstdint>

#define TB 64      // batch
#define TC 64      // input channels
#define TT 1000    // timesteps
#define TH 512     // hidden
#define G4 2048    // 4*H
#define NCLS 5
#define NTHR 512
#define BG 16      // batch per group
#define STEPS 1005 // s = 0..1004  (rec_2 finishes t=999 at s=1004)

__device__ __forceinline__ float sigf(float x) { return 1.0f / (1.0f + expf(-x)); }

// 64-block group barrier. Arrivals RELEASE prior stores (leader threadfence
// flushes XCD L2); waiter ACQUIRE invalidates stale caches.
__device__ __forceinline__ void group_barrier(int* cnt, int* gen) {
  __syncthreads();
  if (threadIdx.x == 0) {
    __threadfence();
    int gsnap = __hip_atomic_load(gen, __ATOMIC_RELAXED, __HIP_MEMORY_SCOPE_AGENT);
    int v = __hip_atomic_fetch_add(cnt, 1, __ATOMIC_ACQ_REL, __HIP_MEMORY_SCOPE_AGENT);
    if (v == 63) {
      __hip_atomic_store(cnt, 0, __ATOMIC_RELAXED, __HIP_MEMORY_SCOPE_AGENT);
      __hip_atomic_fetch_add(gen, 1, __ATOMIC_ACQ_REL, __HIP_MEMORY_SCOPE_AGENT);
    } else {
      while (__hip_atomic_load(gen, __ATOMIC_ACQUIRE, __HIP_MEMORY_SCOPE_AGENT) == gsnap)
        __builtin_amdgcn_s_sleep(2);
    }
  }
  __syncthreads();
}

// Persistent pipelined 3-layer LSTM.
// 256 blocks = 4 batch-groups (16 batches) x 64 slots:
//   slot 0-35 : rec layer l = slot/12   (43/42 cells, K=512 W_hh + pointwise)
//   slot 36-59: proj layer 1+( (slot-36)/12 )  (xg = h_{l-1} @ W_ih^T + bias)
//   slot 60-63: layer-0 proj (K=64 from x directly)
// Pipeline: rec_l at step s does t = s-1-2l; proj_l does t' = s-2l.
// Rolling buffers: hseq[l][t&1][64][512], xgbuf[l][t&1][64][2048].
__global__ __launch_bounds__(NTHR, 2) void lstm_pipe(
    const float* __restrict__ x, const float* __restrict__ Wih0,
    const float* __restrict__ WihR, const float* __restrict__ Whh,
    const float* __restrict__ bih, const float* __restrict__ bhh,
    float* __restrict__ hseq, float* __restrict__ xgbuf, int* __restrict__ bar)
{
  __shared__ float hTile[16][516];       // 33024 B (padded: 2-way-max bank use)
  __shared__ float scratch[4][45][16];   // 11520 B gate exchange (rec only)

  const int tid = threadIdx.x;
  const int blk = blockIdx.x;
  const int grp = blk >> 6;
  const int slot = blk & 63;
  const int b_base = grp * BG;

  int role, lay, sg;
  if (slot < 36)      { role = 0; lay = slot / 12;        sg = slot - 12 * lay; }
  else if (slot < 60) { role = 1; lay = 1 + (slot - 36) / 12; sg = (slot - 36) % 12; }
  else                { role = 2; lay = 0;                sg = slot - 60; }

  int c_lo, nc;
  if (role == 2)      { c_lo = sg * 128;            nc = 128; }
  else if (sg < 8)    { c_lo = 43 * sg;             nc = 43;  }
  else                { c_lo = 344 + 42 * (sg - 8); nc = 42;  }

  const int rr = tid >> 4;   // 0..31 (row-thread)
  const int b  = tid & 15;   // batch within group
  const int g  = rr & 3;     // gate (i,f,g,o)
  const int cr = rr >> 2;    // 0..7 cell base
  // rows r = rr + 32m  ->  gate g, local cell cr + 8m. nr is wave-uniform.
  const int nr = (role == 2) ? 0 : ((4 * nc - rr + 31) >> 5);

  int* cnt = bar + grp * 64;
  int* gen = bar + grp * 64 + 16;

  const float* WL = nullptr;
  float pb6[6];
  float l0bias = 0.f;
  const int lg = tid & 3;        // l0proj: gate
  const int lc = tid >> 2;       // l0proj: local cell 0..127
  if (role == 0) {
    WL = Whh + (size_t)lay * G4 * TH;
  } else if (role == 1) {
    WL = WihR + (size_t)(lay - 1) * G4 * TH;
#pragma unroll
    for (int m = 0; m < 6; ++m) if (m < nr) {
      int rowg = g * TH + c_lo + cr + 8 * m;
      pb6[m] = bih[lay * G4 + rowg] + bhh[lay * G4 + rowg];
    }
  } else {
    int rowg = lg * TH + c_lo + lc;
    l0bias = bih[rowg] + bhh[rowg];
  }

  float cst[2] = {0.f, 0.f};   // cell state for up to 2 pointwise tasks

  for (int s = 0; s < STEPS; ++s) {
    if (role == 0) {
      const int t = s - 1 - 2 * lay;
      if (t >= 0 && t < TT) {
        if (t > 0) {   // stage h_l[t-1]
          const float* hs = hseq + ((size_t)(lay * 2 + ((t - 1) & 1)) * TB + b_base) * TH;
          const int brow = tid >> 5, k4 = tid & 31;
#pragma unroll
          for (int kk = 0; kk < 4; ++kk)
            *(float4*)&hTile[brow][(k4 + 32 * kk) * 4] =
                *(const float4*)&hs[(size_t)brow * TH + (k4 + 32 * kk) * 4];
        }
        __syncthreads();
        float acc[6];
#pragma unroll
        for (int m = 0; m < 6; ++m) acc[m] = 0.f;
        if (t > 0) {
          const float* wp = WL + (size_t)(g * TH + c_lo + cr) * TH;
          for (int k = 0; k < TH; k += 4) {
            float4 h4 = *(const float4*)&hTile[b][k];
#pragma unroll
            for (int m = 0; m < 6; ++m) if (m < nr) {
              float4 w4 = *(const float4*)(wp + (size_t)m * (8 * TH) + k);
              acc[m] = fmaf(w4.x, h4.x, acc[m]); acc[m] = fmaf(w4.y, h4.y, acc[m]);
              acc[m] = fmaf(w4.z, h4.z, acc[m]); acc[m] = fmaf(w4.w, h4.w, acc[m]);
            }
          }
        }
#pragma unroll
        for (int m = 0; m < 6; ++m) if (m < nr) scratch[g][cr + 8 * m][b] = acc[m];
        __syncthreads();
        const float* xg = xgbuf + ((size_t)(lay * 2 + (t & 1)) * TB + b_base) * G4;
        float* hw = hseq + ((size_t)(lay * 2 + (t & 1)) * TB + b_base) * TH;
#pragma unroll
        for (int j = 0; j < 2; ++j) {
          int p = tid + j * NTHR;
          if (p < 16 * nc) {
            int cell = p >> 4, pb = p & 15;
            size_t xo = (size_t)pb * G4 + c_lo + cell;
            float ai = scratch[0][cell][pb] + xg[xo];
            float af = scratch[1][cell][pb] + xg[xo + TH];
            float ag = scratch[2][cell][pb] + xg[xo + 2 * TH];
            float ao = scratch[3][cell][pb] + xg[xo + 3 * TH];
            float ii = sigf(ai), ff = sigf(af), gg = tanhf(ag), oo = sigf(ao);
            float cs = (t > 0) ? fmaf(ff, cst[j], ii * gg) : ii * gg;
            cst[j] = cs;
            hw[(size_t)pb * TH + c_lo + cell] = oo * tanhf(cs);
          }
        }
      }
    } else if (role == 1) {
      const int tp = s - 2 * lay;
      if (tp >= 0 && tp < TT) {
        const float* hs = hseq + ((size_t)((lay - 1) * 2 + (tp & 1)) * TB + b_base) * TH;
        const int brow = tid >> 5, k4 = tid & 31;
#pragma unroll
        for (int kk = 0; kk < 4; ++kk)
          *(float4*)&hTile[brow][(k4 + 32 * kk) * 4] =
              *(const float4*)&hs[(size_t)brow * TH + (k4 + 32 * kk) * 4];
        __syncthreads();
        float acc[6];
#pragma unroll
        for (int m = 0; m < 6; ++m) acc[m] = (m < nr) ? pb6[m] : 0.f;
        const float* wp = WL + (size_t)(g * TH + c_lo + cr) * TH;
        for (int k = 0; k < TH; k += 4) {
          float4 h4 = *(const float4*)&hTile[b][k];
#pragma unroll
          for (int m = 0; m < 6; ++m) if (m < nr) {
            float4 w4 = *(const float4*)(wp + (size_t)m * (8 * TH) + k);
            acc[m] = fmaf(w4.x, h4.x, acc[m]); acc[m] = fmaf(w4.y, h4.y, acc[m]);
            acc[m] = fmaf(w4.z, h4.z, acc[m]); acc[m] = fmaf(w4.w, h4.w, acc[m]);
          }
        }
        float* xg = xgbuf + ((size_t)(lay * 2 + (tp & 1)) * TB + b_base) * G4;
#pragma unroll
        for (int m = 0; m < 6; ++m) if (m < nr)
          xg[(size_t)b * G4 + g * TH + c_lo + cr + 8 * m] = acc[m];
      }
    } else {
      const int tp = s;
      if (tp < TT) {
        float* xt = &hTile[0][0];   // reuse as [16][68]
#pragma unroll
        for (int q = 0; q < 2; ++q) {
          int i = tid + q * NTHR;   // 0..1023
          int bb = i >> 6, ch = i & 63;
          xt[bb * 68 + ch] = x[(size_t)(b_base + bb) * TC * TT + (size_t)ch * TT + tp];
        }
        __syncthreads();
        float accb[16];
#pragma unroll
        for (int q = 0; q < 16; ++q) accb[q] = l0bias;
        const float* wp = Wih0 + (size_t)(lg * TH + c_lo + lc) * TC;
#pragma unroll
        for (int k = 0; k < TC; k += 4) {
          float4 w4 = *(const float4*)(wp + k);
#pragma unroll
          for (int q = 0; q < 16; ++q) {
            float4 xv = *(const float4*)&xt[q * 68 + k];
            accb[q] = fmaf(w4.x, xv.x, accb[q]); accb[q] = fmaf(w4.y, xv.y, accb[q]);
            accb[q] = fmaf(w4.z, xv.z, accb[q]); accb[q] = fmaf(w4.w, xv.w, accb[q]);
          }
        }
        float* xg = xgbuf + ((size_t)(tp & 1) * TB + b_base) * G4;
#pragma unroll
        for (int q = 0; q < 16; ++q)
          xg[(size_t)q * G4 + lg * TH + c_lo + lc] = accb[q];
      }
    }
    group_barrier(cnt, gen);
  }
}

__global__ void fc_kernel(const float* __restrict__ hseq, const float* __restrict__ Wfc,
                          const float* __restrict__ bfc, float* __restrict__ out) {
  int bb = blockIdx.x, lane = threadIdx.x;
  const float* h = hseq + ((size_t)5 * TB + bb) * TH;   // layer2, parity (999&1)=1
  for (int n = 0; n < NCLS; ++n) {
    float s = 0.f;
    for (int k = lane; k < TH; k += 64) s = fmaf(h[k], Wfc[n * TH + k], s);
    for (int off = 32; off > 0; off >>= 1) s += __shfl_down(s, off, 64);
    if (lane == 0) out[bb * NCLS + n] = s + bfc[n];
  }
}

extern "C" void kernel_launch(void* const* d_in, const int* in_sizes, int n_in,
                              void* d_out, int out_size, void* d_ws, size_t ws_size,
                              hipStream_t stream) {
  const float* x    = (const float*)d_in[0];
  const float* Wih0 = (const float*)d_in[1];
  const float* WihR = (const float*)d_in[2];
  const float* Whh  = (const float*)d_in[3];
  const float* bih  = (const float*)d_in[4];
  const float* bhh  = (const float*)d_in[5];
  const float* Wfc  = (const float*)d_in[6];
  const float* bfc  = (const float*)d_in[7];
  float* out = (float*)d_out;

  char* ws = (char*)d_ws;
  int*   bar   = (int*)ws;                        // 1 KB: 4 groups x 64 ints
  float* hseq  = (float*)(ws + 1024);             // [3][2][64][512]  = 768 KB
  float* xgbuf = hseq + (size_t)6 * TB * TH;      // [3][2][64][2048] = 3 MB
  // total d_ws use: ~3.93 MB

  hipMemsetAsync(bar, 0, 1024, stream);
  lstm_pipe<<<256, NTHR, 0, stream>>>(x, Wih0, WihR, Whh, bih, bhh, hseq, xgbuf, bar);
  fc_kernel<<<TB, 64, 0, stream>>>(hseq, Wfc, bfc, out);
}

// Round 3
// 116767.847 us; speedup vs baseline: 1.7242x; 1.7242x over previous
//
#include <hip/hip_runtime.h>
#include <cstdint>

#define TB 64      // batch
#define TC 64      // input channels
#define TT 1000    // timesteps
#define TH 512     // hidden
#define G4 2048    // 4*H
#define NCLS 5
#define NTHR 512
#define BG 16      // batch per group
#define STEPS 1005 // s = 0..1004  (rec_2 finishes t=999 at s=1004)

__device__ __forceinline__ float sigf(float x) { return 1.0f / (1.0f + expf(-x)); }

// ---- coherent (L3-direct) memory ops: bypass L1/L2 via sc0 sc1 ----
__device__ __forceinline__ int load_i_cg(const int* p) {
  int v;
  asm volatile("global_load_dword %0, %1, off sc0 sc1\n\ts_waitcnt vmcnt(0)"
               : "=v"(v) : "v"(p) : "memory");
  return v;
}

__device__ __forceinline__ void stage4_cg(const float* p0, const float* p1,
                                          const float* p2, const float* p3,
                                          float4& v0, float4& v1, float4& v2, float4& v3) {
  asm volatile(
      "global_load_dwordx4 %0, %4, off sc0 sc1\n\t"
      "global_load_dwordx4 %1, %5, off sc0 sc1\n\t"
      "global_load_dwordx4 %2, %6, off sc0 sc1\n\t"
      "global_load_dwordx4 %3, %7, off sc0 sc1\n\t"
      "s_waitcnt vmcnt(0)"
      : "=&v"(v0), "=&v"(v1), "=&v"(v2), "=&v"(v3)
      : "v"(p0), "v"(p1), "v"(p2), "v"(p3)
      : "memory");
}

__device__ __forceinline__ void load4_cg(const float* p0, const float* p1,
                                         const float* p2, const float* p3,
                                         float& a, float& b, float& c, float& d) {
  asm volatile(
      "global_load_dword %0, %4, off sc0 sc1\n\t"
      "global_load_dword %1, %5, off sc0 sc1\n\t"
      "global_load_dword %2, %6, off sc0 sc1\n\t"
      "global_load_dword %3, %7, off sc0 sc1\n\t"
      "s_waitcnt vmcnt(0)"
      : "=&v"(a), "=&v"(b), "=&v"(c), "=&v"(d)
      : "v"(p0), "v"(p1), "v"(p2), "v"(p3)
      : "memory");
}

__device__ __forceinline__ void store_cg(float* p, float v) {
  asm volatile("global_store_dword %0, %1, off sc0 sc1" :: "v"(p), "v"(v) : "memory");
}

// 64-block group barrier, fence-free.
// Arrivals: relaxed RMW (executes at coherence point). Data ordering: the
// __syncthreads() before arrival drains vmcnt (sc1 stores ack'd from L3).
// Reset via fetch_add(-64): commutative, never loses a racing next-step arrival.
// Spin: explicit sc0sc1 load (no cache invalidation per poll).
__device__ __forceinline__ void group_barrier(int* cnt, int* gen) {
  __syncthreads();
  if (threadIdx.x == 0) {
    int g = load_i_cg(gen);
    int v = __hip_atomic_fetch_add(cnt, 1, __ATOMIC_RELAXED, __HIP_MEMORY_SCOPE_AGENT);
    if (v == 63) {
      __hip_atomic_fetch_add(cnt, -64, __ATOMIC_RELAXED, __HIP_MEMORY_SCOPE_AGENT);
      __hip_atomic_fetch_add(gen, 1, __ATOMIC_RELAXED, __HIP_MEMORY_SCOPE_AGENT);
    } else {
      while (load_i_cg(gen) == g) __builtin_amdgcn_s_sleep(1);
    }
  }
  __syncthreads();
}

// Persistent pipelined 3-layer LSTM.
// 256 blocks = 4 batch-groups (16 batches) x 64 slots:
//   slot 0-35 : rec layer l = slot/12   (43/42 cells, K=512 W_hh + pointwise)
//   slot 36-59: proj layer 1+( (slot-36)/12 )  (xg = h_{l-1} @ W_ih^T + bias)
//   slot 60-63: layer-0 proj (K=64 from x directly)
// Pipeline: rec_l at step s does t = s-1-2l; proj_l does t' = s-2l.
// Rolling buffers: hseq[l][t&1][64][512], xgbuf[l][t&1][64][2048]  (all sc0sc1).
// Weights/biases/x: normal cached loads -> L2-resident (no invalidations ever).
__global__ __launch_bounds__(NTHR, 2) void lstm_pipe(
    const float* __restrict__ x, const float* __restrict__ Wih0,
    const float* __restrict__ WihR, const float* __restrict__ Whh,
    const float* __restrict__ bih, const float* __restrict__ bhh,
    float* __restrict__ hseq, float* __restrict__ xgbuf, int* __restrict__ bar)
{
  __shared__ float hTile[16][516];       // 33024 B (padded: conflict-free b128)
  __shared__ float scratch[4][45][16];   // 11520 B gate exchange (rec only)

  const int tid = threadIdx.x;
  const int blk = blockIdx.x;
  const int grp = blk >> 6;
  const int slot = blk & 63;
  const int b_base = grp * BG;

  int role, lay, sg;
  if (slot < 36)      { role = 0; lay = slot / 12;        sg = slot - 12 * lay; }
  else if (slot < 60) { role = 1; lay = 1 + (slot - 36) / 12; sg = (slot - 36) % 12; }
  else                { role = 2; lay = 0;                sg = slot - 60; }

  int c_lo, nc;
  if (role == 2)      { c_lo = sg * 128;            nc = 128; }
  else if (sg < 8)    { c_lo = 43 * sg;             nc = 43;  }
  else                { c_lo = 344 + 42 * (sg - 8); nc = 42;  }

  const int rr = tid >> 4;   // 0..31 (row-thread)
  const int b  = tid & 15;   // batch within group
  const int g  = rr & 3;     // gate (i,f,g,o)
  const int cr = rr >> 2;    // 0..7 cell base
  const int nr = (role == 2) ? 0 : ((4 * nc - rr + 31) >> 5);

  int* cnt = bar + grp * 64;
  int* gen = bar + grp * 64 + 16;

  const float* WL = nullptr;
  float pb6[6];
  float l0bias = 0.f;
  const int lg = tid & 3;        // l0proj: gate
  const int lc = tid >> 2;       // l0proj: local cell 0..127
  if (role == 0) {
    WL = Whh + (size_t)lay * G4 * TH;
  } else if (role == 1) {
    WL = WihR + (size_t)(lay - 1) * G4 * TH;
#pragma unroll
    for (int m = 0; m < 6; ++m) if (m < nr) {
      int rowg = g * TH + c_lo + cr + 8 * m;
      pb6[m] = bih[lay * G4 + rowg] + bhh[lay * G4 + rowg];
    }
  } else {
    int rowg = lg * TH + c_lo + lc;
    l0bias = bih[rowg] + bhh[rowg];
  }

  float cst[2] = {0.f, 0.f};   // cell state for up to 2 pointwise tasks

  for (int s = 0; s < STEPS; ++s) {
    if (role == 0) {
      const int t = s - 1 - 2 * lay;
      if (t >= 0 && t < TT) {
        if (t > 0) {   // stage h_l[t-1]  (coherent loads -> LDS)
          const float* hs = hseq + ((size_t)(lay * 2 + ((t - 1) & 1)) * TB + b_base) * TH;
          const int brow = tid >> 5, k4 = tid & 31;
          const float* hp = hs + (size_t)brow * TH + k4 * 4;
          float4 v0, v1, v2, v3;
          stage4_cg(hp, hp + 128, hp + 256, hp + 384, v0, v1, v2, v3);
          *(float4*)&hTile[brow][k4 * 4]       = v0;
          *(float4*)&hTile[brow][k4 * 4 + 128] = v1;
          *(float4*)&hTile[brow][k4 * 4 + 256] = v2;
          *(float4*)&hTile[brow][k4 * 4 + 384] = v3;
        }
        __syncthreads();
        float acc[6];
#pragma unroll
        for (int m = 0; m < 6; ++m) acc[m] = 0.f;
        if (t > 0) {
          const float* wp = WL + (size_t)(g * TH + c_lo + cr) * TH;
          for (int k = 0; k < TH; k += 4) {
            float4 h4 = *(const float4*)&hTile[b][k];
#pragma unroll
            for (int m = 0; m < 6; ++m) if (m < nr) {
              float4 w4 = *(const float4*)(wp + (size_t)m * (8 * TH) + k);
              acc[m] = fmaf(w4.x, h4.x, acc[m]); acc[m] = fmaf(w4.y, h4.y, acc[m]);
              acc[m] = fmaf(w4.z, h4.z, acc[m]); acc[m] = fmaf(w4.w, h4.w, acc[m]);
            }
          }
        }
#pragma unroll
        for (int m = 0; m < 6; ++m) if (m < nr) scratch[g][cr + 8 * m][b] = acc[m];
        __syncthreads();
        const float* xg = xgbuf + ((size_t)(lay * 2 + (t & 1)) * TB + b_base) * G4;
        float* hw = hseq + ((size_t)(lay * 2 + (t & 1)) * TB + b_base) * TH;
#pragma unroll
        for (int j = 0; j < 2; ++j) {
          int p = tid + j * NTHR;
          if (p < 16 * nc) {
            int cell = p >> 4, pb = p & 15;
            const float* xgp = xg + (size_t)pb * G4 + c_lo + cell;
            float ai, af, ag, ao;
            load4_cg(xgp, xgp + TH, xgp + 2 * TH, xgp + 3 * TH, ai, af, ag, ao);
            ai += scratch[0][cell][pb];
            af += scratch[1][cell][pb];
            ag += scratch[2][cell][pb];
            ao += scratch[3][cell][pb];
            float ii = sigf(ai), ff = sigf(af), gg = tanhf(ag), oo = sigf(ao);
            float cs = (t > 0) ? fmaf(ff, cst[j], ii * gg) : ii * gg;
            cst[j] = cs;
            store_cg(&hw[(size_t)pb * TH + c_lo + cell], oo * tanhf(cs));
          }
        }
      }
    } else if (role == 1) {
      const int tp = s - 2 * lay;
      if (tp >= 0 && tp < TT) {
        const float* hs = hseq + ((size_t)((lay - 1) * 2 + (tp & 1)) * TB + b_base) * TH;
        const int brow = tid >> 5, k4 = tid & 31;
        const float* hp = hs + (size_t)brow * TH + k4 * 4;
        float4 v0, v1, v2, v3;
        stage4_cg(hp, hp + 128, hp + 256, hp + 384, v0, v1, v2, v3);
        *(float4*)&hTile[brow][k4 * 4]       = v0;
        *(float4*)&hTile[brow][k4 * 4 + 128] = v1;
        *(float4*)&hTile[brow][k4 * 4 + 256] = v2;
        *(float4*)&hTile[brow][k4 * 4 + 384] = v3;
        __syncthreads();
        float acc[6];
#pragma unroll
        for (int m = 0; m < 6; ++m) acc[m] = (m < nr) ? pb6[m] : 0.f;
        const float* wp = WL + (size_t)(g * TH + c_lo + cr) * TH;
        for (int k = 0; k < TH; k += 4) {
          float4 h4 = *(const float4*)&hTile[b][k];
#pragma unroll
          for (int m = 0; m < 6; ++m) if (m < nr) {
            float4 w4 = *(const float4*)(wp + (size_t)m * (8 * TH) + k);
            acc[m] = fmaf(w4.x, h4.x, acc[m]); acc[m] = fmaf(w4.y, h4.y, acc[m]);
            acc[m] = fmaf(w4.z, h4.z, acc[m]); acc[m] = fmaf(w4.w, h4.w, acc[m]);
          }
        }
        float* xg = xgbuf + ((size_t)(lay * 2 + (tp & 1)) * TB + b_base) * G4;
#pragma unroll
        for (int m = 0; m < 6; ++m) if (m < nr)
          store_cg(&xg[(size_t)b * G4 + g * TH + c_lo + cr + 8 * m], acc[m]);
      }
    } else {
      const int tp = s;
      if (tp < TT) {
        float* xt = &hTile[0][0];   // reuse as [16][68]
#pragma unroll
        for (int q = 0; q < 2; ++q) {
          int i = tid + q * NTHR;   // 0..1023
          int bb = i >> 6, ch = i & 63;
          xt[bb * 68 + ch] = x[(size_t)(b_base + bb) * TC * TT + (size_t)ch * TT + tp];
        }
        __syncthreads();
        float accb[16];
#pragma unroll
        for (int q = 0; q < 16; ++q) accb[q] = l0bias;
        const float* wp = Wih0 + (size_t)(lg * TH + c_lo + lc) * TC;
#pragma unroll
        for (int k = 0; k < TC; k += 4) {
          float4 w4 = *(const float4*)(wp + k);
#pragma unroll
          for (int q = 0; q < 16; ++q) {
            float4 xv = *(const float4*)&xt[q * 68 + k];
            accb[q] = fmaf(w4.x, xv.x, accb[q]); accb[q] = fmaf(w4.y, xv.y, accb[q]);
            accb[q] = fmaf(w4.z, xv.z, accb[q]); accb[q] = fmaf(w4.w, xv.w, accb[q]);
          }
        }
        float* xg = xgbuf + ((size_t)(tp & 1) * TB + b_base) * G4;
#pragma unroll
        for (int q = 0; q < 16; ++q)
          store_cg(&xg[(size_t)q * G4 + lg * TH + c_lo + lc], accb[q]);
      }
    }
    group_barrier(cnt, gen);
  }
}

__global__ void fc_kernel(const float* __restrict__ hseq, const float* __restrict__ Wfc,
                          const float* __restrict__ bfc, float* __restrict__ out) {
  int bb = blockIdx.x, lane = threadIdx.x;
  const float* h = hseq + ((size_t)5 * TB + bb) * TH;   // layer2, parity (999&1)=1
  for (int n = 0; n < NCLS; ++n) {
    float s = 0.f;
    for (int k = lane; k < TH; k += 64) s = fmaf(h[k], Wfc[n * TH + k], s);
    for (int off = 32; off > 0; off >>= 1) s += __shfl_down(s, off, 64);
    if (lane == 0) out[bb * NCLS + n] = s + bfc[n];
  }
}

extern "C" void kernel_launch(void* const* d_in, const int* in_sizes, int n_in,
                              void* d_out, int out_size, void* d_ws, size_t ws_size,
                              hipStream_t stream) {
  const float* x    = (const float*)d_in[0];
  const float* Wih0 = (const float*)d_in[1];
  const float* WihR = (const float*)d_in[2];
  const float* Whh  = (const float*)d_in[3];
  const float* bih  = (const float*)d_in[4];
  const float* bhh  = (const float*)d_in[5];
  const float* Wfc  = (const float*)d_in[6];
  const float* bfc  = (const float*)d_in[7];
  float* out = (float*)d_out;

  char* ws = (char*)d_ws;
  int*   bar   = (int*)ws;                        // 1 KB: 4 groups x 64 ints
  float* hseq  = (float*)(ws + 1024);             // [3][2][64][512]  = 768 KB
  float* xgbuf = hseq + (size_t)6 * TB * TH;      // [3][2][64][2048] = 3 MB
  // total d_ws use: ~3.93 MB

  hipMemsetAsync(bar, 0, 1024, stream);
  lstm_pipe<<<256, NTHR, 0, stream>>>(x, Wih0, WihR, Whh, bih, bhh, hseq, xgbuf, bar);
  fc_kernel<<<TB, 64, 0, stream>>>(hseq, Wfc, bfc, out);
}

// Round 9
// 37918.918 us; speedup vs baseline: 5.3094x; 3.0794x over previous
//
#include <hip/hip_runtime.h>
#include <cstdint>

#define TB 64      // batch
#define TC 64      // input channels
#define TT 1000    // timesteps
#define TH 512     // hidden
#define NCLS 5
#define NTHR 512
#define STEPS 1002 // s = 0..1001; layer l computes t = s - l

// LDS float offsets
#define H0_OFF 0            // [16][512]
#define H1_OFF 8192
#define H2_OFF 16384
#define X_OFF  24576        // x chunk: [8 t][16 b][64 c]
#define SC_OFF 32768        // scratch: 8 waves x 864 (l*288 + cl*36 + 4b + g)
#define SC_W   864
#define LDS_FLOATS (SC_OFF + 8 * SC_W)   // 39680
#define LDS_BYTES  (LDS_FLOATS * 4)      // 158720  (fits 160 KiB, 1 block/CU)

__device__ __forceinline__ float sigf(float x) { return 1.0f / (1.0f + expf(-x)); }

// 64-block group barrier — ROUND-9: back to the HIP memory-model protocol that
// was EMPIRICALLY EXACT in round 2, leader-only and once-per-step:
//   all-thread __syncthreads  (compiler drains vmcnt -> stores visible in L2)
//   leader: __threadfence()   (agent release: buffer_wbl2 flushes the XCD L2 ->
//                              every thread's h-store reaches the L3 coherence
//                              point BEFORE the arrival RMW issues)
//   leader: relaxed arrival RMW; RELAXED spin (coherent atomic loads, no
//                              per-poll cache invalidation -> no round-2 storm)
//   leader: __threadfence()   (agent acquire: buffer_inv L1+L2 -> subsequent
//                              plain h-loads must re-fill from L3)
//   all-thread __syncthreads
// Rounds 3-8's sc0sc1 bypass protocol was NOT architecturally sound: a plain
// sc1 store's vmcnt ack does not guarantee L3 visibility (absmax wandered
// 0.07-0.09 across identical-arithmetic builds = race). Weights are in VGPRs,
// so the once-per-step L2 invalidation no longer costs anything material.
__device__ __forceinline__ void group_barrier(int* cnt, int* gen) {
  __syncthreads();
  if (threadIdx.x == 0) {
    __threadfence();   // release: wbL2 + waitcnt
    int g = __hip_atomic_load(gen, __ATOMIC_RELAXED, __HIP_MEMORY_SCOPE_AGENT);
    int v = __hip_atomic_fetch_add(cnt, 1, __ATOMIC_RELAXED, __HIP_MEMORY_SCOPE_AGENT);
    if (v == 63) {
      __hip_atomic_fetch_add(cnt, -64, __ATOMIC_RELAXED, __HIP_MEMORY_SCOPE_AGENT);
      __hip_atomic_fetch_add(gen, 1, __ATOMIC_RELAXED, __HIP_MEMORY_SCOPE_AGENT);
    } else {
      while (__hip_atomic_load(gen, __ATOMIC_RELAXED, __HIP_MEMORY_SCOPE_AGENT) == g)
        __builtin_amdgcn_s_sleep(2);
    }
    __threadfence();   // acquire: inv L1/L2
  }
  __syncthreads();
}

// fmaf dot4 as a function, NOT a macro (round-4 lesson: macro param named `w`
// gets substituted into the `.w` member accessor).
__device__ __forceinline__ void dot4(float& acc, const float4 a, const float4 b) {
  acc = fmaf(a.x, b.x, acc); acc = fmaf(a.y, b.y, acc);
  acc = fmaf(a.z, b.z, acc); acc = fmaf(a.w, b.w, acc);
}

// Persistent fused 3-layer LSTM, register-resident weights.
// 256 blocks = 4 groups (16 batches) x 64 slots; slot owns cells [slot*8, slot*8+8)
// in ALL 3 layers. gates_l(t) = bias + h_{l-1}(t) @ Wih_l^T + h_l(t-1) @ Whh_l^T,
// layer l computes t = s - l at step s. Per step: stage h0(s-1),h1(s-2),h2(s-3)
// (plain cached float4 loads -> LDS; caches were acquire-invalidated at the
// barrier so these re-fill coherently from L3). x staged in 8-step chunks
// (float4-contiguous in t) so per-step L2 invalidation can't thrash it.
// Thread (kk=tid>>5, rt=tid&31): one gate-row per layer (gate rt&3, cell
// slot*8+(rt>>2)), K-slice kk of 16. Weights: 164 floats/thread in VGPRs.
__global__ __launch_bounds__(NTHR, 1) void lstm_pipe(
    const float* __restrict__ x, const float* __restrict__ Wih0,
    const float* __restrict__ WihR, const float* __restrict__ Whh,
    const float* __restrict__ bih, const float* __restrict__ bhh,
    float* __restrict__ hbuf, int* __restrict__ bar)
{
  extern __shared__ float lds[];
  const int tid = threadIdx.x;
  const int blk = blockIdx.x;
  const int grp = blk >> 6, slot = blk & 63;
  const int b_base = grp * 16;
  const int kk = tid >> 5;          // 0..15 K-slice
  const int rt = tid & 31;
  const int g  = rt & 3;            // gate i,f,g,o
  const int cl = rt >> 2;           // 0..7 local cell
  const int cell = slot * 8 + cl;
  const int row  = g * TH + cell;   // gate-row in [2048]
  const int wv = tid >> 6;          // wave 0..7

  int* cnt = bar + grp * 64;
  int* gen = bar + grp * 64 + 16;

  // ---- weights -> registers (164 floats) ----
  float4 wx, wh0[8], w1a[8], w1b[8], w2a[8], w2b[8];
  wx = *(const float4*)(Wih0 + (size_t)row * TC + 4 * kk);
  {
    const float* p0 = Whh  + (size_t)row * TH + 32 * kk;            // Whh[0]
    const float* p1 = WihR + (size_t)row * TH + 32 * kk;            // Wih[1]
    const float* p2 = Whh  + (size_t)(2048 + row) * TH + 32 * kk;   // Whh[1]
    const float* p3 = WihR + (size_t)(2048 + row) * TH + 32 * kk;   // Wih[2]
    const float* p4 = Whh  + (size_t)(4096 + row) * TH + 32 * kk;   // Whh[2]
#pragma unroll
    for (int i = 0; i < 8; ++i) {
      wh0[i] = *(const float4*)(p0 + 4 * i);
      w1a[i] = *(const float4*)(p1 + 4 * i);
      w1b[i] = *(const float4*)(p2 + 4 * i);
      w2a[i] = *(const float4*)(p3 + 4 * i);
      w2b[i] = *(const float4*)(p4 + 4 * i);
    }
  }

  // ---- reducer setup (tid<192: one (layer rl, cell rc, batch rb)) ----
  const int rl = tid >> 6;          // 0..2 when tid<192
  const int rc = (tid & 63) >> 3;   // 0..7
  const int rb = tid & 7;           // 0..7 (batch within pass)
  const int rcell = slot * 8 + rc;
  float4 bias_r = make_float4(0.f, 0.f, 0.f, 0.f);
  if (tid < 192) {
    bias_r.x = bih[rl * 2048 + rcell]        + bhh[rl * 2048 + rcell];
    bias_r.y = bih[rl * 2048 +  512 + rcell] + bhh[rl * 2048 +  512 + rcell];
    bias_r.z = bih[rl * 2048 + 1024 + rcell] + bhh[rl * 2048 + 1024 + rcell];
    bias_r.w = bih[rl * 2048 + 1536 + rcell] + bhh[rl * 2048 + 1536 + rcell];
  }
  float cst0 = 0.f, cst1 = 0.f;     // cell state (pass 0 / pass 1 batch)

  for (int s = 0; s < STEPS; ++s) {
    // ---------- stage tiles (plain cached loads -> regs -> LDS) ----------
    {
      const bool v0 = (s >= 1 && s <= 1000);   // h0(s-1)
      const bool v1 = (s >= 2);                // h1(s-2)
      const bool v2 = (s >= 3);                // h2(s-3)
      const bool vc = ((s & 7) == 0 && s <= 999);  // x chunk [s, s+8)
      float4 t00, t01, t02, t03, t10, t11, t12, t13, t20, t21, t22, t23;
      float4 xa0, xa1, xb0, xb1;
      if (v0) {
        const float4* gp = (const float4*)(hbuf + ((size_t)(0 + ((s - 1) & 1)) * TB + b_base) * TH) + tid;
        t00 = gp[0]; t01 = gp[512]; t02 = gp[1024]; t03 = gp[1536];
      }
      if (v1) {
        const float4* gp = (const float4*)(hbuf + ((size_t)(2 + ((s - 2) & 1)) * TB + b_base) * TH) + tid;
        t10 = gp[0]; t11 = gp[512]; t12 = gp[1024]; t13 = gp[1536];
      }
      if (v2) {
        const float4* gp = (const float4*)(hbuf + ((size_t)(4 + ((s - 3) & 1)) * TB + b_base) * TH) + tid;
        t20 = gp[0]; t21 = gp[512]; t22 = gp[1024]; t23 = gp[1536];
      }
      if (vc) {   // 8 timesteps of x for (b,c) pairs e0=tid, e1=tid+512
        const int e0 = tid, e1 = tid + NTHR;
        const float* q0 = x + (size_t)(b_base + (e0 >> 6)) * (TC * TT) + (size_t)(e0 & 63) * TT + s;
        const float* q1 = x + (size_t)(b_base + (e1 >> 6)) * (TC * TT) + (size_t)(e1 & 63) * TT + s;
        xa0 = *(const float4*)(q0); xa1 = *(const float4*)(q0 + 4);
        xb0 = *(const float4*)(q1); xb1 = *(const float4*)(q1 + 4);
      }
      if (v0) { float4* d = (float4*)(lds + H0_OFF); d[tid] = t00; d[tid + 512] = t01; d[tid + 1024] = t02; d[tid + 1536] = t03; }
      if (v1) { float4* d = (float4*)(lds + H1_OFF); d[tid] = t10; d[tid + 512] = t11; d[tid + 1024] = t12; d[tid + 1536] = t13; }
      if (v2) { float4* d = (float4*)(lds + H2_OFF); d[tid] = t20; d[tid + 512] = t21; d[tid + 1024] = t22; d[tid + 1536] = t23; }
      if (vc) {   // scatter to X[j][b][c]
        const int e0 = tid, e1 = tid + NTHR;
        float* d0 = lds + X_OFF + (e0 >> 6) * 64 + (e0 & 63);
        float* d1 = lds + X_OFF + (e1 >> 6) * 64 + (e1 & 63);
        d0[0 * 1024] = xa0.x; d0[1 * 1024] = xa0.y; d0[2 * 1024] = xa0.z; d0[3 * 1024] = xa0.w;
        d0[4 * 1024] = xa1.x; d0[5 * 1024] = xa1.y; d0[6 * 1024] = xa1.z; d0[7 * 1024] = xa1.w;
        d1[0 * 1024] = xb0.x; d1[1 * 1024] = xb0.y; d1[2 * 1024] = xb0.z; d1[3 * 1024] = xb0.w;
        d1[4 * 1024] = xb1.x; d1[5 * 1024] = xb1.y; d1[6 * 1024] = xb1.z; d1[7 * 1024] = xb1.w;
      }
    }
    __syncthreads();

    // ---------- compute: 2 passes of 8 batches ----------
#pragma unroll
    for (int p = 0; p < 2; ++p) {
      float a0[8], a1[8], a2[8];
#pragma unroll
      for (int b = 0; b < 8; ++b) { a0[b] = 0.f; a1[b] = 0.f; a2[b] = 0.f; }
#pragma unroll
      for (int b = 0; b < 8; ++b) {
        const int bb = p * 8 + b;
        if (s <= 999) {
          float4 xf = *(const float4*)(lds + X_OFF + (s & 7) * 1024 + bb * 64 + 4 * kk);
          dot4(a0[b], wx, xf);
        }
        if (s >= 1 && s <= 1000) {
          const float* hb = lds + H0_OFF + bb * TH + 32 * kk;
#pragma unroll
          for (int c4 = 0; c4 < 2; ++c4) {
            float4 f0 = *(const float4*)(hb + 16 * c4 + 0);
            float4 f1 = *(const float4*)(hb + 16 * c4 + 4);
            float4 f2 = *(const float4*)(hb + 16 * c4 + 8);
            float4 f3 = *(const float4*)(hb + 16 * c4 + 12);
            if (s <= 999) {
              dot4(a0[b], wh0[4 * c4 + 0], f0); dot4(a0[b], wh0[4 * c4 + 1], f1);
              dot4(a0[b], wh0[4 * c4 + 2], f2); dot4(a0[b], wh0[4 * c4 + 3], f3);
            }
            dot4(a1[b], w1a[4 * c4 + 0], f0); dot4(a1[b], w1a[4 * c4 + 1], f1);
            dot4(a1[b], w1a[4 * c4 + 2], f2); dot4(a1[b], w1a[4 * c4 + 3], f3);
          }
        }
        if (s >= 2) {
          const float* hb = lds + H1_OFF + bb * TH + 32 * kk;
#pragma unroll
          for (int c4 = 0; c4 < 2; ++c4) {
            float4 f0 = *(const float4*)(hb + 16 * c4 + 0);
            float4 f1 = *(const float4*)(hb + 16 * c4 + 4);
            float4 f2 = *(const float4*)(hb + 16 * c4 + 8);
            float4 f3 = *(const float4*)(hb + 16 * c4 + 12);
            if (s <= 1000) {
              dot4(a1[b], w1b[4 * c4 + 0], f0); dot4(a1[b], w1b[4 * c4 + 1], f1);
              dot4(a1[b], w1b[4 * c4 + 2], f2); dot4(a1[b], w1b[4 * c4 + 3], f3);
            }
            dot4(a2[b], w2a[4 * c4 + 0], f0); dot4(a2[b], w2a[4 * c4 + 1], f1);
            dot4(a2[b], w2a[4 * c4 + 2], f2); dot4(a2[b], w2a[4 * c4 + 3], f3);
          }
        }
        if (s >= 3) {
          const float* hb = lds + H2_OFF + bb * TH + 32 * kk;
#pragma unroll
          for (int c4 = 0; c4 < 2; ++c4) {
            float4 f0 = *(const float4*)(hb + 16 * c4 + 0);
            float4 f1 = *(const float4*)(hb + 16 * c4 + 4);
            float4 f2 = *(const float4*)(hb + 16 * c4 + 8);
            float4 f3 = *(const float4*)(hb + 16 * c4 + 12);
            dot4(a2[b], w2b[4 * c4 + 0], f0); dot4(a2[b], w2b[4 * c4 + 1], f1);
            dot4(a2[b], w2b[4 * c4 + 2], f2); dot4(a2[b], w2b[4 * c4 + 3], f3);
          }
        }
      }
      // kk-pair reduce (lane ^ 32), then LDS scratch (conflict-free stride 36)
#pragma unroll
      for (int b = 0; b < 8; ++b) {
        a0[b] += __shfl_xor(a0[b], 32, 64);
        a1[b] += __shfl_xor(a1[b], 32, 64);
        a2[b] += __shfl_xor(a2[b], 32, 64);
      }
      if ((tid & 32) == 0) {
        float* sb = lds + SC_OFF + wv * SC_W + cl * 36 + g;
#pragma unroll
        for (int b = 0; b < 8; ++b) {
          sb[4 * b]       = a0[b];
          sb[288 + 4 * b] = a1[b];
          sb[576 + 4 * b] = a2[b];
        }
      }
      __syncthreads();
      if (tid < 192) {
        const int tl = s - rl;
        if (tl >= 0 && tl < TT) {
          float sx = 0.f, sy = 0.f, sz = 0.f, sw = 0.f;
          const float* sb = lds + SC_OFF + rl * 288 + rc * 36 + 4 * rb;
#pragma unroll
          for (int w8 = 0; w8 < 8; ++w8) {
            float4 v = *(const float4*)(sb + w8 * SC_W);
            sx += v.x; sy += v.y; sz += v.z; sw += v.w;
          }
          float ii = sigf(sx + bias_r.x);
          float ff = sigf(sy + bias_r.y);
          float gg = tanhf(sz + bias_r.z);
          float oo = sigf(sw + bias_r.w);
          float cprev = p ? cst1 : cst0;
          float cc = (tl == 0) ? ii * gg : fmaf(ff, cprev, ii * gg);
          if (p) cst1 = cc; else cst0 = cc;
          float hh = oo * tanhf(cc);
          hbuf[((size_t)(rl * 2 + (tl & 1)) * TB + b_base + p * 8 + rb) * TH + rcell] = hh;
        }
      }
      __syncthreads();
    }
    group_barrier(cnt, gen);
  }
}

__global__ void fc_kernel(const float* __restrict__ hbuf, const float* __restrict__ Wfc,
                          const float* __restrict__ bfc, float* __restrict__ out) {
  int bb = blockIdx.x, lane = threadIdx.x;
  const float* h = hbuf + ((size_t)5 * TB + bb) * TH;   // layer2, parity (999&1)=1
  for (int n = 0; n < NCLS; ++n) {
    float s = 0.f;
    for (int k = lane; k < TH; k += 64) s = fmaf(h[k], Wfc[n * TH + k], s);
    for (int off = 32; off > 0; off >>= 1) s += __shfl_down(s, off, 64);
    if (lane == 0) out[bb * NCLS + n] = s + bfc[n];
  }
}

extern "C" void kernel_launch(void* const* d_in, const int* in_sizes, int n_in,
                              void* d_out, int out_size, void* d_ws, size_t ws_size,
                              hipStream_t stream) {
  const float* x    = (const float*)d_in[0];
  const float* Wih0 = (const float*)d_in[1];
  const float* WihR = (const float*)d_in[2];
  const float* Whh  = (const float*)d_in[3];
  const float* bih  = (const float*)d_in[4];
  const float* bhh  = (const float*)d_in[5];
  const float* Wfc  = (const float*)d_in[6];
  const float* bfc  = (const float*)d_in[7];
  float* out = (float*)d_out;

  char* ws = (char*)d_ws;
  int*   bar  = (int*)ws;                             // 1 KB: 4 groups x 64 ints
  float* hbuf = (float*)(ws + 1024);                  // [3][2][64][512] = 768 KB
  // total d_ws use: 769 KB

  hipMemsetAsync(bar, 0, 1024, stream);
  hipFuncSetAttribute((const void*)lstm_pipe,
                      hipFuncAttributeMaxDynamicSharedMemorySize, LDS_BYTES);
  lstm_pipe<<<256, NTHR, LDS_BYTES, stream>>>(x, Wih0, WihR, Whh, bih, bhh, hbuf, bar);
  fc_kernel<<<TB, 64, 0, stream>>>(hbuf, Wfc, bfc, out);
}

// Round 10
// 29413.773 us; speedup vs baseline: 6.8446x; 1.2892x over previous
//
#include <hip/hip_runtime.h>
#include <cstdint>

#define TB 64      // batch
#define TC 64      // input channels
#define TT 1000    // timesteps
#define TH 512     // hidden
#define NCLS 5
#define NTHR 512
#define STEPS 1002 // s = 0..1001; layer l computes t = s - l

// LDS float offsets
#define H0_OFF 0            // [16][512]
#define H1_OFF 8192
#define H2_OFF 16384
#define X_OFF  24576        // x chunk: [8 t][16 b][64 c]
#define SC_OFF 32768        // scratch: 8 waves x 864 (l*288 + cl*36 + 4b + g)
#define SC_W   864
#define LDS_FLOATS (SC_OFF + 8 * SC_W)   // 39680
#define LDS_BYTES  (LDS_FLOATS * 4)      // 158720  (fits 160 KiB, 1 block/CU)

__device__ __forceinline__ float sigf(float x) { return 1.0f / (1.0f + expf(-x)); }

// 64-block group barrier — round-9 proven EXACT (absmax 0.0):
//   all-thread __syncthreads (drains vmcnt -> stores in L2)
//   leader: __threadfence()  release (wbL2 -> h-stores reach L3 coherence point)
//   leader: relaxed arrival RMW; RELAXED spin (no per-poll invalidation storm)
//   leader: __threadfence()  acquire (inv L1/L2 -> later loads re-fill from L3)
//   all-thread __syncthreads
__device__ __forceinline__ void group_barrier(int* cnt, int* gen) {
  __syncthreads();
  if (threadIdx.x == 0) {
    __threadfence();   // release: wbL2 + waitcnt
    int g = __hip_atomic_load(gen, __ATOMIC_RELAXED, __HIP_MEMORY_SCOPE_AGENT);
    int v = __hip_atomic_fetch_add(cnt, 1, __ATOMIC_RELAXED, __HIP_MEMORY_SCOPE_AGENT);
    if (v == 63) {
      __hip_atomic_fetch_add(cnt, -64, __ATOMIC_RELAXED, __HIP_MEMORY_SCOPE_AGENT);
      __hip_atomic_fetch_add(gen, 1, __ATOMIC_RELAXED, __HIP_MEMORY_SCOPE_AGENT);
    } else {
      while (__hip_atomic_load(gen, __ATOMIC_RELAXED, __HIP_MEMORY_SCOPE_AGENT) == g)
        __builtin_amdgcn_s_sleep(2);
    }
    __threadfence();   // acquire: inv L1/L2
  }
  __syncthreads();
}

// fmaf dot4 as a function, NOT a macro (round-4 lesson: macro param named `w`
// gets substituted into the `.w` member accessor).
__device__ __forceinline__ void dot4(float& acc, const float4 a, const float4 b) {
  acc = fmaf(a.x, b.x, acc); acc = fmaf(a.y, b.y, acc);
  acc = fmaf(a.z, b.z, acc); acc = fmaf(a.w, b.w, acc);
}

// direct global->LDS (16B/lane): dest = wave-uniform lds base + lane*16.
__device__ __forceinline__ void gload_lds16(const char* gsrc_lane, char* lds_base) {
  __builtin_amdgcn_global_load_lds(
      (const __attribute__((address_space(1))) unsigned int*)gsrc_lane,
      (__attribute__((address_space(3))) unsigned int*)lds_base, 16, 0, 0);
}

// Persistent fused 3-layer LSTM, register-resident weights.
// ROUND-10: de-spill. Round 9 passed exact at 38 ms but VGPR_Count=128 with
// 25 GB/dispatch of HBM writes = weight spill to scratch, re-flushed every step
// by the barrier's wbL2. Fixes: (a) amdgpu_waves_per_eu(2,2) — occupancy is
// LDS-forced to 2 waves/EU anyway, so let the allocator use the full 256-VGPR
// budget; (b) stage h tiles via global_load_lds (no VGPR round-trip, -48 regs
// of staging temps). Structure otherwise identical to round 9.
__global__ __launch_bounds__(NTHR) __attribute__((amdgpu_waves_per_eu(2, 2)))
void lstm_pipe(
    const float* __restrict__ x, const float* __restrict__ Wih0,
    const float* __restrict__ WihR, const float* __restrict__ Whh,
    const float* __restrict__ bih, const float* __restrict__ bhh,
    float* __restrict__ hbuf, int* __restrict__ bar)
{
  extern __shared__ float lds[];
  const int tid = threadIdx.x;
  const int blk = blockIdx.x;
  const int grp = blk >> 6, slot = blk & 63;
  const int b_base = grp * 16;
  const int kk = tid >> 5;          // 0..15 K-slice
  const int rt = tid & 31;
  const int g  = rt & 3;            // gate i,f,g,o
  const int cl = rt >> 2;           // 0..7 local cell
  const int cell = slot * 8 + cl;
  const int row  = g * TH + cell;   // gate-row in [2048]
  const int wv = tid >> 6;          // wave 0..7
  const int lane = tid & 63;

  int* cnt = bar + grp * 64;
  int* gen = bar + grp * 64 + 16;

  // ---- weights -> registers (164 floats) ----
  float4 wx, wh0[8], w1a[8], w1b[8], w2a[8], w2b[8];
  wx = *(const float4*)(Wih0 + (size_t)row * TC + 4 * kk);
  {
    const float* p0 = Whh  + (size_t)row * TH + 32 * kk;            // Whh[0]
    const float* p1 = WihR + (size_t)row * TH + 32 * kk;            // Wih[1]
    const float* p2 = Whh  + (size_t)(2048 + row) * TH + 32 * kk;   // Whh[1]
    const float* p3 = WihR + (size_t)(2048 + row) * TH + 32 * kk;   // Wih[2]
    const float* p4 = Whh  + (size_t)(4096 + row) * TH + 32 * kk;   // Whh[2]
#pragma unroll
    for (int i = 0; i < 8; ++i) {
      wh0[i] = *(const float4*)(p0 + 4 * i);
      w1a[i] = *(const float4*)(p1 + 4 * i);
      w1b[i] = *(const float4*)(p2 + 4 * i);
      w2a[i] = *(const float4*)(p3 + 4 * i);
      w2b[i] = *(const float4*)(p4 + 4 * i);
    }
  }

  // ---- reducer setup (tid<192: one (layer rl, cell rc, batch rb)) ----
  const int rl = tid >> 6;          // 0..2 when tid<192
  const int rc = (tid & 63) >> 3;   // 0..7
  const int rb = tid & 7;           // 0..7 (batch within pass)
  const int rcell = slot * 8 + rc;
  float4 bias_r = make_float4(0.f, 0.f, 0.f, 0.f);
  if (tid < 192) {
    bias_r.x = bih[rl * 2048 + rcell]        + bhh[rl * 2048 + rcell];
    bias_r.y = bih[rl * 2048 +  512 + rcell] + bhh[rl * 2048 +  512 + rcell];
    bias_r.z = bih[rl * 2048 + 1024 + rcell] + bhh[rl * 2048 + 1024 + rcell];
    bias_r.w = bih[rl * 2048 + 1536 + rcell] + bhh[rl * 2048 + 1536 + rcell];
  }
  float cst0 = 0.f, cst1 = 0.f;     // cell state (pass 0 / pass 1 batch)

  for (int s = 0; s < STEPS; ++s) {
    // ---------- stage tiles ----------
    {
      const bool v0 = (s >= 1 && s <= 1000);       // h0(s-1)
      const bool v1 = (s >= 2);                    // h1(s-2)
      const bool v2 = (s >= 3);                    // h2(s-3)
      const bool vc = ((s & 7) == 0 && s <= 999);  // x chunk [s, s+8)
      // h tiles: direct global->LDS, 4 chunks of 1 KB per wave per tile
      if (v0) {
        const char* gp = (const char*)(hbuf + ((size_t)(0 + ((s - 1) & 1)) * TB + b_base) * TH);
        char* lb = (char*)lds + H0_OFF * 4;
#pragma unroll
        for (int i = 0; i < 4; ++i) {
          int off = wv * 4096 + i * 1024;
          gload_lds16(gp + off + lane * 16, lb + off);
        }
      }
      if (v1) {
        const char* gp = (const char*)(hbuf + ((size_t)(2 + ((s - 2) & 1)) * TB + b_base) * TH);
        char* lb = (char*)lds + H1_OFF * 4;
#pragma unroll
        for (int i = 0; i < 4; ++i) {
          int off = wv * 4096 + i * 1024;
          gload_lds16(gp + off + lane * 16, lb + off);
        }
      }
      if (v2) {
        const char* gp = (const char*)(hbuf + ((size_t)(4 + ((s - 3) & 1)) * TB + b_base) * TH);
        char* lb = (char*)lds + H2_OFF * 4;
#pragma unroll
        for (int i = 0; i < 4; ++i) {
          int off = wv * 4096 + i * 1024;
          gload_lds16(gp + off + lane * 16, lb + off);
        }
      }
      if (vc) {   // 8 timesteps of x for (b,c) pairs e0=tid, e1=tid+512 (reg path)
        const int e0 = tid, e1 = tid + NTHR;
        const float* q0 = x + (size_t)(b_base + (e0 >> 6)) * (TC * TT) + (size_t)(e0 & 63) * TT + s;
        const float* q1 = x + (size_t)(b_base + (e1 >> 6)) * (TC * TT) + (size_t)(e1 & 63) * TT + s;
        float4 xa0 = *(const float4*)(q0), xa1 = *(const float4*)(q0 + 4);
        float4 xb0 = *(const float4*)(q1), xb1 = *(const float4*)(q1 + 4);
        float* d0 = lds + X_OFF + (e0 >> 6) * 64 + (e0 & 63);
        float* d1 = lds + X_OFF + (e1 >> 6) * 64 + (e1 & 63);
        d0[0 * 1024] = xa0.x; d0[1 * 1024] = xa0.y; d0[2 * 1024] = xa0.z; d0[3 * 1024] = xa0.w;
        d0[4 * 1024] = xa1.x; d0[5 * 1024] = xa1.y; d0[6 * 1024] = xa1.z; d0[7 * 1024] = xa1.w;
        d1[0 * 1024] = xb0.x; d1[1 * 1024] = xb0.y; d1[2 * 1024] = xb0.z; d1[3 * 1024] = xb0.w;
        d1[4 * 1024] = xb1.x; d1[5 * 1024] = xb1.y; d1[6 * 1024] = xb1.z; d1[7 * 1024] = xb1.w;
      }
    }
    __syncthreads();

    // ---------- compute: 2 passes of 8 batches ----------
#pragma unroll
    for (int p = 0; p < 2; ++p) {
      float a0[8], a1[8], a2[8];
#pragma unroll
      for (int b = 0; b < 8; ++b) { a0[b] = 0.f; a1[b] = 0.f; a2[b] = 0.f; }
#pragma unroll
      for (int b = 0; b < 8; ++b) {
        const int bb = p * 8 + b;
        if (s <= 999) {
          float4 xf = *(const float4*)(lds + X_OFF + (s & 7) * 1024 + bb * 64 + 4 * kk);
          dot4(a0[b], wx, xf);
        }
        if (s >= 1 && s <= 1000) {
          const float* hb = lds + H0_OFF + bb * TH + 32 * kk;
#pragma unroll
          for (int c4 = 0; c4 < 2; ++c4) {
            float4 f0 = *(const float4*)(hb + 16 * c4 + 0);
            float4 f1 = *(const float4*)(hb + 16 * c4 + 4);
            float4 f2 = *(const float4*)(hb + 16 * c4 + 8);
            float4 f3 = *(const float4*)(hb + 16 * c4 + 12);
            if (s <= 999) {
              dot4(a0[b], wh0[4 * c4 + 0], f0); dot4(a0[b], wh0[4 * c4 + 1], f1);
              dot4(a0[b], wh0[4 * c4 + 2], f2); dot4(a0[b], wh0[4 * c4 + 3], f3);
            }
            dot4(a1[b], w1a[4 * c4 + 0], f0); dot4(a1[b], w1a[4 * c4 + 1], f1);
            dot4(a1[b], w1a[4 * c4 + 2], f2); dot4(a1[b], w1a[4 * c4 + 3], f3);
          }
        }
        if (s >= 2) {
          const float* hb = lds + H1_OFF + bb * TH + 32 * kk;
#pragma unroll
          for (int c4 = 0; c4 < 2; ++c4) {
            float4 f0 = *(const float4*)(hb + 16 * c4 + 0);
            float4 f1 = *(const float4*)(hb + 16 * c4 + 4);
            float4 f2 = *(const float4*)(hb + 16 * c4 + 8);
            float4 f3 = *(const float4*)(hb + 16 * c4 + 12);
            if (s <= 1000) {
              dot4(a1[b], w1b[4 * c4 + 0], f0); dot4(a1[b], w1b[4 * c4 + 1], f1);
              dot4(a1[b], w1b[4 * c4 + 2], f2); dot4(a1[b], w1b[4 * c4 + 3], f3);
            }
            dot4(a2[b], w2a[4 * c4 + 0], f0); dot4(a2[b], w2a[4 * c4 + 1], f1);
            dot4(a2[b], w2a[4 * c4 + 2], f2); dot4(a2[b], w2a[4 * c4 + 3], f3);
          }
        }
        if (s >= 3) {
          const float* hb = lds + H2_OFF + bb * TH + 32 * kk;
#pragma unroll
          for (int c4 = 0; c4 < 2; ++c4) {
            float4 f0 = *(const float4*)(hb + 16 * c4 + 0);
            float4 f1 = *(const float4*)(hb + 16 * c4 + 4);
            float4 f2 = *(const float4*)(hb + 16 * c4 + 8);
            float4 f3 = *(const float4*)(hb + 16 * c4 + 12);
            dot4(a2[b], w2b[4 * c4 + 0], f0); dot4(a2[b], w2b[4 * c4 + 1], f1);
            dot4(a2[b], w2b[4 * c4 + 2], f2); dot4(a2[b], w2b[4 * c4 + 3], f3);
          }
        }
      }
      // kk-pair reduce (lane ^ 32), then LDS scratch (conflict-free stride 36)
#pragma unroll
      for (int b = 0; b < 8; ++b) {
        a0[b] += __shfl_xor(a0[b], 32, 64);
        a1[b] += __shfl_xor(a1[b], 32, 64);
        a2[b] += __shfl_xor(a2[b], 32, 64);
      }
      if ((tid & 32) == 0) {
        float* sb = lds + SC_OFF + wv * SC_W + cl * 36 + g;
#pragma unroll
        for (int b = 0; b < 8; ++b) {
          sb[4 * b]       = a0[b];
          sb[288 + 4 * b] = a1[b];
          sb[576 + 4 * b] = a2[b];
        }
      }
      __syncthreads();
      if (tid < 192) {
        const int tl = s - rl;
        if (tl >= 0 && tl < TT) {
          float sx = 0.f, sy = 0.f, sz = 0.f, sw = 0.f;
          const float* sb = lds + SC_OFF + rl * 288 + rc * 36 + 4 * rb;
#pragma unroll
          for (int w8 = 0; w8 < 8; ++w8) {
            float4 v = *(const float4*)(sb + w8 * SC_W);
            sx += v.x; sy += v.y; sz += v.z; sw += v.w;
          }
          float ii = sigf(sx + bias_r.x);
          float ff = sigf(sy + bias_r.y);
          float gg = tanhf(sz + bias_r.z);
          float oo = sigf(sw + bias_r.w);
          float cprev = p ? cst1 : cst0;
          float cc = (tl == 0) ? ii * gg : fmaf(ff, cprev, ii * gg);
          if (p) cst1 = cc; else cst0 = cc;
          float hh = oo * tanhf(cc);
          hbuf[((size_t)(rl * 2 + (tl & 1)) * TB + b_base + p * 8 + rb) * TH + rcell] = hh;
        }
      }
      __syncthreads();
    }
    group_barrier(cnt, gen);
  }
}

__global__ void fc_kernel(const float* __restrict__ hbuf, const float* __restrict__ Wfc,
                          const float* __restrict__ bfc, float* __restrict__ out) {
  int bb = blockIdx.x, lane = threadIdx.x;
  const float* h = hbuf + ((size_t)5 * TB + bb) * TH;   // layer2, parity (999&1)=1
  for (int n = 0; n < NCLS; ++n) {
    float s = 0.f;
    for (int k = lane; k < TH; k += 64) s = fmaf(h[k], Wfc[n * TH + k], s);
    for (int off = 32; off > 0; off >>= 1) s += __shfl_down(s, off, 64);
    if (lane == 0) out[bb * NCLS + n] = s + bfc[n];
  }
}

extern "C" void kernel_launch(void* const* d_in, const int* in_sizes, int n_in,
                              void* d_out, int out_size, void* d_ws, size_t ws_size,
                              hipStream_t stream) {
  const float* x    = (const float*)d_in[0];
  const float* Wih0 = (const float*)d_in[1];
  const float* WihR = (const float*)d_in[2];
  const float* Whh  = (const float*)d_in[3];
  const float* bih  = (const float*)d_in[4];
  const float* bhh  = (const float*)d_in[5];
  const float* Wfc  = (const float*)d_in[6];
  const float* bfc  = (const float*)d_in[7];
  float* out = (float*)d_out;

  char* ws = (char*)d_ws;
  int*   bar  = (int*)ws;                             // 1 KB: 4 groups x 64 ints
  float* hbuf = (float*)(ws + 1024);                  // [3][2][64][512] = 768 KB
  // total d_ws use: 769 KB

  hipMemsetAsync(bar, 0, 1024, stream);
  hipFuncSetAttribute((const void*)lstm_pipe,
                      hipFuncAttributeMaxDynamicSharedMemorySize, LDS_BYTES);
  lstm_pipe<<<256, NTHR, LDS_BYTES, stream>>>(x, Wih0, WihR, Whh, bih, bhh, hbuf, bar);
  fc_kernel<<<TB, 64, 0, stream>>>(hbuf, Wfc, bfc, out);
}

// Round 11
// 24956.554 us; speedup vs baseline: 8.0670x; 1.1786x over previous
//
#include <hip/hip_runtime.h>
#include <cstdint>

#define TB 64      // batch
#define TC 64      // input channels
#define TT 1000    // timesteps
#define TH 512     // hidden
#define NCLS 5
#define NTHR 512
#define STEPS 1002 // s = 0..1001; layer l computes t = s - l

// LDS float offsets
#define H0_OFF 0            // [16][512]
#define H1_OFF 8192
#define H2_OFF 16384
#define X_OFF  24576        // x chunk: [8 t][16 b][64 c]
#define SC_OFF 32768        // scratch: 8 waves x 864 (l*288 + cl*36 + 4b + g)
#define SC_W   864
#define LDS_FLOATS (SC_OFF + 8 * SC_W)   // 39680
#define LDS_BYTES  (LDS_FLOATS * 4)      // 158720  (fits 160 KiB, 1 block/CU)

__device__ __forceinline__ float sigf(float x) { return 1.0f / (1.0f + expf(-x)); }

// 64-block group barrier — ROUND-11: release-only coherence.
// Store side (UNCHANGED, proven exact in rounds 2/9/10):
//   all-thread __syncthreads (drains stores into L2)
//   leader: __threadfence()  release (wbL2 -> h-stores reach the L3 coherence
//           point BEFORE the arrival RMW issues)
//   leader: relaxed arrival RMW; relaxed spin
// Load side (NEW): NO acquire fence. The per-step L1+L2 invalidation forced
// the compiler's rematerialized weight loads (VGPR=128 -> weights NOT register
// resident) to re-stream ~84 MB/step from L3. Each XCD hosts only 8 unique
// slots (blk and blk+64k map to the same XCD since 64%8==0) = 2.6 MB unique
// weights -> L2-resident once we stop invalidating. Correctness: the ONLY
// cross-block data is hbuf, and its reads go L3-direct (sc0 sc1 cpol on
// global_load_lds), bypassing any stale L1/L2 line. Release put the data in
// L3 before the gen bump; spin sees bump -> L3-direct read sees fresh h.
__device__ __forceinline__ void group_barrier(int* cnt, int* gen) {
  __syncthreads();
  if (threadIdx.x == 0) {
    __threadfence();   // release: wbL2 + waitcnt (keeps clean lines: wb, not wbinv)
    int g = __hip_atomic_load(gen, __ATOMIC_RELAXED, __HIP_MEMORY_SCOPE_AGENT);
    int v = __hip_atomic_fetch_add(cnt, 1, __ATOMIC_RELAXED, __HIP_MEMORY_SCOPE_AGENT);
    if (v == 63) {
      __hip_atomic_fetch_add(cnt, -64, __ATOMIC_RELAXED, __HIP_MEMORY_SCOPE_AGENT);
      __hip_atomic_fetch_add(gen, 1, __ATOMIC_RELAXED, __HIP_MEMORY_SCOPE_AGENT);
    } else {
      while (__hip_atomic_load(gen, __ATOMIC_RELAXED, __HIP_MEMORY_SCOPE_AGENT) == g)
        __builtin_amdgcn_s_sleep(2);
    }
    // no acquire: L1/L2 never invalidated; read-only data stays cache-resident
  }
  __syncthreads();
}

// fmaf dot4 as a function, NOT a macro (round-4 lesson: macro param named `w`
// gets substituted into the `.w` member accessor).
__device__ __forceinline__ void dot4(float& acc, const float4 a, const float4 b) {
  acc = fmaf(a.x, b.x, acc); acc = fmaf(a.y, b.y, acc);
  acc = fmaf(a.z, b.z, acc); acc = fmaf(a.w, b.w, acc);
}

// direct global->LDS (16B/lane), L3-coherent read: aux=0x11 = SC0|SC1 cpol
// (gfx94x encoding: SC0=bit0, SC1=bit4) -> bypasses L1 and L2 on the read path.
__device__ __forceinline__ void gload_lds16_cg(const char* gsrc_lane, char* lds_base) {
  __builtin_amdgcn_global_load_lds(
      (const __attribute__((address_space(1))) unsigned int*)gsrc_lane,
      (__attribute__((address_space(3))) unsigned int*)lds_base, 16, 0, 0x11);
}

// Persistent fused 3-layer LSTM (structure of rounds 9/10, proven exact).
__global__ __launch_bounds__(NTHR) __attribute__((amdgpu_waves_per_eu(2, 2)))
void lstm_pipe(
    const float* __restrict__ x, const float* __restrict__ Wih0,
    const float* __restrict__ WihR, const float* __restrict__ Whh,
    const float* __restrict__ bih, const float* __restrict__ bhh,
    float* __restrict__ hbuf, int* __restrict__ bar)
{
  extern __shared__ float lds[];
  const int tid = threadIdx.x;
  const int blk = blockIdx.x;
  const int grp = blk >> 6, slot = blk & 63;
  const int b_base = grp * 16;
  const int kk = tid >> 5;          // 0..15 K-slice
  const int rt = tid & 31;
  const int g  = rt & 3;            // gate i,f,g,o
  const int cl = rt >> 2;           // 0..7 local cell
  const int cell = slot * 8 + cl;
  const int row  = g * TH + cell;   // gate-row in [2048]
  const int wv = tid >> 6;          // wave 0..7
  const int lane = tid & 63;

  int* cnt = bar + grp * 64;
  int* gen = bar + grp * 64 + 16;

  // ---- weights -> registers (compiler may remat; now L2-hits, not L3) ----
  float4 wx, wh0[8], w1a[8], w1b[8], w2a[8], w2b[8];
  wx = *(const float4*)(Wih0 + (size_t)row * TC + 4 * kk);
  {
    const float* p0 = Whh  + (size_t)row * TH + 32 * kk;            // Whh[0]
    const float* p1 = WihR + (size_t)row * TH + 32 * kk;            // Wih[1]
    const float* p2 = Whh  + (size_t)(2048 + row) * TH + 32 * kk;   // Whh[1]
    const float* p3 = WihR + (size_t)(2048 + row) * TH + 32 * kk;   // Wih[2]
    const float* p4 = Whh  + (size_t)(4096 + row) * TH + 32 * kk;   // Whh[2]
#pragma unroll
    for (int i = 0; i < 8; ++i) {
      wh0[i] = *(const float4*)(p0 + 4 * i);
      w1a[i] = *(const float4*)(p1 + 4 * i);
      w1b[i] = *(const float4*)(p2 + 4 * i);
      w2a[i] = *(const float4*)(p3 + 4 * i);
      w2b[i] = *(const float4*)(p4 + 4 * i);
    }
  }

  // ---- reducer setup (tid<192: one (layer rl, cell rc, batch rb)) ----
  const int rl = tid >> 6;          // 0..2 when tid<192
  const int rc = (tid & 63) >> 3;   // 0..7
  const int rb = tid & 7;           // 0..7 (batch within pass)
  const int rcell = slot * 8 + rc;
  float4 bias_r = make_float4(0.f, 0.f, 0.f, 0.f);
  if (tid < 192) {
    bias_r.x = bih[rl * 2048 + rcell]        + bhh[rl * 2048 + rcell];
    bias_r.y = bih[rl * 2048 +  512 + rcell] + bhh[rl * 2048 +  512 + rcell];
    bias_r.z = bih[rl * 2048 + 1024 + rcell] + bhh[rl * 2048 + 1024 + rcell];
    bias_r.w = bih[rl * 2048 + 1536 + rcell] + bhh[rl * 2048 + 1536 + rcell];
  }
  float cst0 = 0.f, cst1 = 0.f;     // cell state (pass 0 / pass 1 batch)

  for (int s = 0; s < STEPS; ++s) {
    // ---------- stage tiles ----------
    {
      const bool v0 = (s >= 1 && s <= 1000);       // h0(s-1)
      const bool v1 = (s >= 2);                    // h1(s-2)
      const bool v2 = (s >= 3);                    // h2(s-3)
      const bool vc = ((s & 7) == 0 && s <= 999);  // x chunk [s, s+8)
      // h tiles: direct global->LDS with sc0sc1 (L3-coherent read)
      if (v0) {
        const char* gp = (const char*)(hbuf + ((size_t)(0 + ((s - 1) & 1)) * TB + b_base) * TH);
        char* lb = (char*)lds + H0_OFF * 4;
#pragma unroll
        for (int i = 0; i < 4; ++i) {
          int off = wv * 4096 + i * 1024;
          gload_lds16_cg(gp + off + lane * 16, lb + off);
        }
      }
      if (v1) {
        const char* gp = (const char*)(hbuf + ((size_t)(2 + ((s - 2) & 1)) * TB + b_base) * TH);
        char* lb = (char*)lds + H1_OFF * 4;
#pragma unroll
        for (int i = 0; i < 4; ++i) {
          int off = wv * 4096 + i * 1024;
          gload_lds16_cg(gp + off + lane * 16, lb + off);
        }
      }
      if (v2) {
        const char* gp = (const char*)(hbuf + ((size_t)(4 + ((s - 3) & 1)) * TB + b_base) * TH);
        char* lb = (char*)lds + H2_OFF * 4;
#pragma unroll
        for (int i = 0; i < 4; ++i) {
          int off = wv * 4096 + i * 1024;
          gload_lds16_cg(gp + off + lane * 16, lb + off);
        }
      }
      if (vc) {   // 8 timesteps of x for (b,c) pairs e0=tid, e1=tid+512 (plain cached)
        const int e0 = tid, e1 = tid + NTHR;
        const float* q0 = x + (size_t)(b_base + (e0 >> 6)) * (TC * TT) + (size_t)(e0 & 63) * TT + s;
        const float* q1 = x + (size_t)(b_base + (e1 >> 6)) * (TC * TT) + (size_t)(e1 & 63) * TT + s;
        float4 xa0 = *(const float4*)(q0), xa1 = *(const float4*)(q0 + 4);
        float4 xb0 = *(const float4*)(q1), xb1 = *(const float4*)(q1 + 4);
        float* d0 = lds + X_OFF + (e0 >> 6) * 64 + (e0 & 63);
        float* d1 = lds + X_OFF + (e1 >> 6) * 64 + (e1 & 63);
        d0[0 * 1024] = xa0.x; d0[1 * 1024] = xa0.y; d0[2 * 1024] = xa0.z; d0[3 * 1024] = xa0.w;
        d0[4 * 1024] = xa1.x; d0[5 * 1024] = xa1.y; d0[6 * 1024] = xa1.z; d0[7 * 1024] = xa1.w;
        d1[0 * 1024] = xb0.x; d1[1 * 1024] = xb0.y; d1[2 * 1024] = xb0.z; d1[3 * 1024] = xb0.w;
        d1[4 * 1024] = xb1.x; d1[5 * 1024] = xb1.y; d1[6 * 1024] = xb1.z; d1[7 * 1024] = xb1.w;
      }
    }
    __syncthreads();

    // ---------- compute: 2 passes of 8 batches ----------
#pragma unroll
    for (int p = 0; p < 2; ++p) {
      float a0[8], a1[8], a2[8];
#pragma unroll
      for (int b = 0; b < 8; ++b) { a0[b] = 0.f; a1[b] = 0.f; a2[b] = 0.f; }
#pragma unroll
      for (int b = 0; b < 8; ++b) {
        const int bb = p * 8 + b;
        if (s <= 999) {
          float4 xf = *(const float4*)(lds + X_OFF + (s & 7) * 1024 + bb * 64 + 4 * kk);
          dot4(a0[b], wx, xf);
        }
        if (s >= 1 && s <= 1000) {
          const float* hb = lds + H0_OFF + bb * TH + 32 * kk;
#pragma unroll
          for (int c4 = 0; c4 < 2; ++c4) {
            float4 f0 = *(const float4*)(hb + 16 * c4 + 0);
            float4 f1 = *(const float4*)(hb + 16 * c4 + 4);
            float4 f2 = *(const float4*)(hb + 16 * c4 + 8);
            float4 f3 = *(const float4*)(hb + 16 * c4 + 12);
            if (s <= 999) {
              dot4(a0[b], wh0[4 * c4 + 0], f0); dot4(a0[b], wh0[4 * c4 + 1], f1);
              dot4(a0[b], wh0[4 * c4 + 2], f2); dot4(a0[b], wh0[4 * c4 + 3], f3);
            }
            dot4(a1[b], w1a[4 * c4 + 0], f0); dot4(a1[b], w1a[4 * c4 + 1], f1);
            dot4(a1[b], w1a[4 * c4 + 2], f2); dot4(a1[b], w1a[4 * c4 + 3], f3);
          }
        }
        if (s >= 2) {
          const float* hb = lds + H1_OFF + bb * TH + 32 * kk;
#pragma unroll
          for (int c4 = 0; c4 < 2; ++c4) {
            float4 f0 = *(const float4*)(hb + 16 * c4 + 0);
            float4 f1 = *(const float4*)(hb + 16 * c4 + 4);
            float4 f2 = *(const float4*)(hb + 16 * c4 + 8);
            float4 f3 = *(const float4*)(hb + 16 * c4 + 12);
            if (s <= 1000) {
              dot4(a1[b], w1b[4 * c4 + 0], f0); dot4(a1[b], w1b[4 * c4 + 1], f1);
              dot4(a1[b], w1b[4 * c4 + 2], f2); dot4(a1[b], w1b[4 * c4 + 3], f3);
            }
            dot4(a2[b], w2a[4 * c4 + 0], f0); dot4(a2[b], w2a[4 * c4 + 1], f1);
            dot4(a2[b], w2a[4 * c4 + 2], f2); dot4(a2[b], w2a[4 * c4 + 3], f3);
          }
        }
        if (s >= 3) {
          const float* hb = lds + H2_OFF + bb * TH + 32 * kk;
#pragma unroll
          for (int c4 = 0; c4 < 2; ++c4) {
            float4 f0 = *(const float4*)(hb + 16 * c4 + 0);
            float4 f1 = *(const float4*)(hb + 16 * c4 + 4);
            float4 f2 = *(const float4*)(hb + 16 * c4 + 8);
            float4 f3 = *(const float4*)(hb + 16 * c4 + 12);
            dot4(a2[b], w2b[4 * c4 + 0], f0); dot4(a2[b], w2b[4 * c4 + 1], f1);
            dot4(a2[b], w2b[4 * c4 + 2], f2); dot4(a2[b], w2b[4 * c4 + 3], f3);
          }
        }
      }
      // kk-pair reduce (lane ^ 32), then LDS scratch (conflict-free stride 36)
#pragma unroll
      for (int b = 0; b < 8; ++b) {
        a0[b] += __shfl_xor(a0[b], 32, 64);
        a1[b] += __shfl_xor(a1[b], 32, 64);
        a2[b] += __shfl_xor(a2[b], 32, 64);
      }
      if ((tid & 32) == 0) {
        float* sb = lds + SC_OFF + wv * SC_W + cl * 36 + g;
#pragma unroll
        for (int b = 0; b < 8; ++b) {
          sb[4 * b]       = a0[b];
          sb[288 + 4 * b] = a1[b];
          sb[576 + 4 * b] = a2[b];
        }
      }
      __syncthreads();
      if (tid < 192) {
        const int tl = s - rl;
        if (tl >= 0 && tl < TT) {
          float sx = 0.f, sy = 0.f, sz = 0.f, sw = 0.f;
          const float* sb = lds + SC_OFF + rl * 288 + rc * 36 + 4 * rb;
#pragma unroll
          for (int w8 = 0; w8 < 8; ++w8) {
            float4 v = *(const float4*)(sb + w8 * SC_W);
            sx += v.x; sy += v.y; sz += v.z; sw += v.w;
          }
          float ii = sigf(sx + bias_r.x);
          float ff = sigf(sy + bias_r.y);
          float gg = tanhf(sz + bias_r.z);
          float oo = sigf(sw + bias_r.w);
          float cprev = p ? cst1 : cst0;
          float cc = (tl == 0) ? ii * gg : fmaf(ff, cprev, ii * gg);
          if (p) cst1 = cc; else cst0 = cc;
          float hh = oo * tanhf(cc);
          hbuf[((size_t)(rl * 2 + (tl & 1)) * TB + b_base + p * 8 + rb) * TH + rcell] = hh;
        }
      }
      __syncthreads();
    }
    group_barrier(cnt, gen);
  }
}

__global__ void fc_kernel(const float* __restrict__ hbuf, const float* __restrict__ Wfc,
                          const float* __restrict__ bfc, float* __restrict__ out) {
  int bb = blockIdx.x, lane = threadIdx.x;
  const float* h = hbuf + ((size_t)5 * TB + bb) * TH;   // layer2, parity (999&1)=1
  for (int n = 0; n < NCLS; ++n) {
    float s = 0.f;
    for (int k = lane; k < TH; k += 64) s = fmaf(h[k], Wfc[n * TH + k], s);
    for (int off = 32; off > 0; off >>= 1) s += __shfl_down(s, off, 64);
    if (lane == 0) out[bb * NCLS + n] = s + bfc[n];
  }
}

extern "C" void kernel_launch(void* const* d_in, const int* in_sizes, int n_in,
                              void* d_out, int out_size, void* d_ws, size_t ws_size,
                              hipStream_t stream) {
  const float* x    = (const float*)d_in[0];
  const float* Wih0 = (const float*)d_in[1];
  const float* WihR = (const float*)d_in[2];
  const float* Whh  = (const float*)d_in[3];
  const float* bih  = (const float*)d_in[4];
  const float* bhh  = (const float*)d_in[5];
  const float* Wfc  = (const float*)d_in[6];
  const float* bfc  = (const float*)d_in[7];
  float* out = (float*)d_out;

  char* ws = (char*)d_ws;
  int*   bar  = (int*)ws;                             // 1 KB: 4 groups x 64 ints
  float* hbuf = (float*)(ws + 1024);                  // [3][2][64][512] = 768 KB
  // total d_ws use: 769 KB

  hipMemsetAsync(bar, 0, 1024, stream);
  hipFuncSetAttribute((const void*)lstm_pipe,
                      hipFuncAttributeMaxDynamicSharedMemorySize, LDS_BYTES);
  lstm_pipe<<<256, NTHR, LDS_BYTES, stream>>>(x, Wih0, WihR, Whh, bih, bhh, hbuf, bar);
  fc_kernel<<<TB, 64, 0, stream>>>(hbuf, Wfc, bfc, out);
}